// Round 2
// baseline (293.727 us; speedup 1.0000x reference)
//
#include <hip/hip_runtime.h>

// ---- static problem config (mirrors reference init) ----
#define BB   4
#define NNC  4          // cameras
#define DDEP 41
#define FHH  16
#define FWW  44
#define CC   64
#define NXX  240
#define NYY  240
#define NVOX (BB*NYY*NXX)            // 230400 BEV cells (vz==0 plane)
#define NTRI (BB*NNC*DDEP*FWW)       // 28864 (b,n,d,u) column triples; < 2^15
#define SLOTS 8                      // max triples per cell (geometric bound ~4)

// ---- workspace layout (bytes) ----
#define W_CNT  0                         // uint cntp[NVOX/4]  (byte-packed counts)
#define W_TAB  (NVOX)                    // uint table[NVOX][SLOTS]  ((tri<<16)|mask)
// total = 230400 + 7372800 ~= 7.6 MB

typedef float f4 __attribute__((ext_vector_type(4)));

// Replicate LAPACK sgetrf+strti2 on an UPPER-TRIANGULAR 3x3 in fp32, op-for-op.
__device__ __forceinline__ void inv3x3_upper_f32(const float K[9], float o[9]) {
    float a00 = __fdiv_rn(1.0f, K[0]);
    float a11 = __fdiv_rn(1.0f, K[4]);
    float a22 = __fdiv_rn(1.0f, K[8]);
    float b01 = __fmul_rn(-a11, __fmul_rn(a00, K[1]));
    float x0 = __fadd_rn(__fmul_rn(a00, K[2]), __fmul_rn(b01, K[5]));
    float x1 = __fmul_rn(a11, K[5]);
    float b02 = __fmul_rn(-a22, x0);
    float b12 = __fmul_rn(-a22, x1);
    o[0]=a00; o[1]=b01; o[2]=b02;
    o[3]=0.0f; o[4]=a11; o[5]=b12;
    o[6]=0.0f; o[7]=0.0f; o[8]=a22;
}

// Pure-arithmetic geometry (UNCHANGED — bit-exact numerics verified).
__global__ void __launch_bounds__(256) geom(
        const float* __restrict__ rots,
        const float* __restrict__ trans,
        const float* __restrict__ intrins,
        const float* __restrict__ post_rots,
        const float* __restrict__ post_trans,
        unsigned int* __restrict__ cntp,
        unsigned int* __restrict__ table) {
    int wid  = threadIdx.x >> 6;
    int lane = threadIdx.x & 63;
    int sub  = lane >> 4;
    int h    = lane & 15;
    int tri  = (blockIdx.x*4 + wid)*4 + sub;     // NTRI = 16*1804 exactly

    int w    = tri % FWW;
    int rest = tri / FWW;
    int d    = rest % DDEP;
    int bn   = rest / DDEP;

    float K[9], PR[9], R[9];
    #pragma unroll
    for (int i = 0; i < 9; ++i) {
        K[i]  = intrins[bn*9 + i];
        PR[i] = post_rots[bn*9 + i];
        R[i]  = rots[bn*9 + i];
    }
    float Ki[9], PRi[9];
    inv3x3_upper_f32(K, Ki);
    inv3x3_upper_f32(PR, PRi);
    float C[9];
    #pragma unroll
    for (int i = 0; i < 3; ++i)
        #pragma unroll
        for (int j = 0; j < 3; ++j) {
            float s = __fmul_rn(R[i*3+0], Ki[0*3+j]);
            s = __fadd_rn(s, __fmul_rn(R[i*3+1], Ki[1*3+j]));
            s = __fadd_rn(s, __fmul_rn(R[i*3+2], Ki[2*3+j]));
            C[i*3+j] = s;
        }
    float ptx = post_trans[bn*3+0], pty = post_trans[bn*3+1], ptz = post_trans[bn*3+2];
    float trx = trans[bn*3+0], try_ = trans[bn*3+1], trz = trans[bn*3+2];

    float u  = (float)((double)w * (703.0/43.0));   // np.linspace: f64 then f32 cast
    float v  = (float)((double)h * 17.0);
    float dd = (float)(4 + d);

    float p0x = __fsub_rn(u,  ptx);
    float p0y = __fsub_rn(v,  pty);
    float p0z = __fsub_rn(dd, ptz);
    float p1x = __fadd_rn(__fadd_rn(__fmul_rn(PRi[0],p0x), __fmul_rn(PRi[1],p0y)), __fmul_rn(PRi[2],p0z));
    float p1y = __fadd_rn(__fadd_rn(__fmul_rn(PRi[3],p0x), __fmul_rn(PRi[4],p0y)), __fmul_rn(PRi[5],p0z));
    float p1z = __fadd_rn(__fadd_rn(__fmul_rn(PRi[6],p0x), __fmul_rn(PRi[7],p0y)), __fmul_rn(PRi[8],p0z));
    float p2x = __fmul_rn(p1x, p1z);
    float p2y = __fmul_rn(p1y, p1z);
    float p2z = p1z;
    float ex = __fadd_rn(__fadd_rn(__fmul_rn(C[0],p2x), __fmul_rn(C[1],p2y)), __fmul_rn(C[2],p2z));
    float ey = __fadd_rn(__fadd_rn(__fmul_rn(C[3],p2x), __fmul_rn(C[4],p2y)), __fmul_rn(C[5],p2z));
    float ez = __fadd_rn(__fadd_rn(__fmul_rn(C[6],p2x), __fmul_rn(C[7],p2y)), __fmul_rn(C[8],p2z));
    float gx = __fadd_rn(ex, trx);
    float gy = __fadd_rn(ey, try_);
    float gz = __fadd_rn(ez, trz);

    float qx = __fdiv_rn(__fsub_rn(gx, -48.0f), 0.4f);
    float qy = __fdiv_rn(__fsub_rn(gy, -48.0f), 0.4f);
    float qz = __fdiv_rn(__fsub_rn(gz, -10.0f), 20.0f);
    int vx = (int)qx;   // trunc toward zero == astype(int32)
    int vy = (int)qy;
    int vz = (int)qz;

    bool kept = (vx >= 0) & (vx < NXX) & (vy >= 0) & (vy < NYY) & (vz == 0);
    unsigned long long bal = __ballot(kept);
    unsigned int mask = (unsigned int)((bal >> (sub*16)) & 0xFFFFull);

    if (h == 0 && mask != 0) {
        int b  = bn / NNC;
        int vb = b*(NYY*NXX) + vy*NXX + vx;
        unsigned int sh  = 8u*(vb & 3);
        unsigned int old = atomicAdd(&cntp[vb >> 2], 1u << sh);
        unsigned int sl  = (old >> sh) & 0xFFu;
        if (sl < SLOTS) table[vb*SLOTS + sl] = ((unsigned int)tri << 16) | mask;
    }
}

// v3: one block per BEV y-row (240 cells) — see theory in commit message.
// Zero phase streams 960 B runs per c-plane (predicated at 64 B group lines);
// dirty 16-cell groups go one-per-wave with coalesced table fetch, identical
// per-cell summation order, per-wave LDS transpose, no block barriers.
__global__ void __launch_bounds__(256) assemble(
        const float* __restrict__ x,
        const unsigned int* __restrict__ cntp,
        const unsigned int* __restrict__ table,
        float* __restrict__ out) {
    __shared__ float lds[4][16*68];          // per-wave transpose buffer (17.4 KB)
    int tid  = threadIdx.x;
    int lane = tid & 63;
    int wid  = tid >> 6;
    int row  = blockIdx.x;                   // b*NYY + y  (960 rows)
    int cellbase = row * NXX;                // == b*57600 + y*240
    int b   = row / NYY;
    int rowoff = (row - b*NYY) * NXX;        // y*240
    float* outb = out + (size_t)b*(CC*NYY*NXX);

    // one ballot over the row's 60 byte-packed count words -> 15-bit dirty mask
    unsigned int cword = (lane < 60) ? cntp[(cellbase >> 2) + lane] : 0u;
    unsigned long long nz = __ballot(cword != 0u);
    unsigned int dirty = 0u;
    #pragma unroll
    for (int g = 0; g < 15; ++g)
        dirty |= ((((unsigned int)(nz >> (4*g))) & 0xFu) ? 1u : 0u) << g;

    // ---- zero phase: stream zeros, skipping dirty 64 B groups ----
    {
        f4 z = (f4)(0.0f);
        #pragma unroll
        for (int i = 0; i < 15; ++i) {
            int s = i*256 + tid;             // 0..3839 : (c, f4-slot r)
            int c = s / 60;
            int r = s - c*60;
            if (!((dirty >> (r >> 2)) & 1u))
                __builtin_nontemporal_store(z,
                    (f4*)(outb + (size_t)c*(NYY*NXX) + rowoff + r*4));
        }
    }

    // ---- dirty phase: one 16-cell group per wave, round-robin ----
    float* ldsw = &lds[wid][0];
    int hq = lane >> 4;                      // image-row group (0..3)
    int c4 = lane & 15;                      // channel quad
    unsigned int dmask = dirty;
    int gi = 0;
    while (dmask) {
        int g = __ffs(dmask) - 1;
        dmask &= dmask - 1;
        if ((gi++ & 3) != wid) continue;

        int v0 = cellbase + g*16;
        const uint4 cq = *(const uint4*)(cntp + (v0 >> 2));
        unsigned long long cnt_lo = (unsigned long long)cq.x | ((unsigned long long)cq.y << 32);
        unsigned long long cnt_hi = (unsigned long long)cq.z | ((unsigned long long)cq.w << 32);
        // all 128 table slots of the group: 512 B, 2 coalesced loads
        unsigned int ent0 = table[(size_t)v0*SLOTS + lane];
        unsigned int ent1 = table[(size_t)v0*SLOTS + 64 + lane];

        #pragma unroll 2
        for (int k = 0; k < 16; ++k) {
            unsigned long long cw = (k < 8) ? cnt_lo : cnt_hi;
            int n = (int)((cw >> (8*(k & 7))) & 0xFFull); if (n > SLOTS) n = SLOTS;
            f4 acc = (f4)(0.0f);
            for (int i = 0; i < n; ++i) {
                int slot = k*SLOTS + i;      // flat slot index 0..127
                unsigned int e = (unsigned int)__shfl(
                    (int)((slot < 64) ? ent0 : ent1), slot & 63);
                int tri  = (int)(e >> 16);
                unsigned int m = e & 0xFFFFu;
                int w    = tri % FWW;
                int rest = tri / FWW;
                int d    = rest % DDEP;
                int bn   = rest / DDEP;
                const float* xb = x + (size_t)((bn*DDEP + d)*FHH*FWW + w)*CC + c4*4;
                #pragma unroll
                for (int r = 0; r < 4; ++r) {
                    int h = r*4 + hq;
                    if ((m >> h) & 1u) {
                        f4 t = *(const f4*)(xb + (size_t)h*(FWW*CC));
                        acc += t;
                    }
                }
            }
            // sum the 4 hq groups (same order as v2 -> identical rounding)
            acc.x += __shfl_xor(acc.x, 16); acc.y += __shfl_xor(acc.y, 16);
            acc.z += __shfl_xor(acc.z, 16); acc.w += __shfl_xor(acc.w, 16);
            acc.x += __shfl_xor(acc.x, 32); acc.y += __shfl_xor(acc.y, 32);
            acc.z += __shfl_xor(acc.z, 32); acc.w += __shfl_xor(acc.w, 32);
            if (lane < 16)
                *(f4*)&ldsw[k*68 + lane*4] = acc;    // row k = cell, col = channel
        }
        // wave-local transpose out: 4 passes, 16 c-planes each, 64 B segments
        #pragma unroll
        for (int p = 0; p < 4; ++p) {
            int c = p*16 + (lane >> 2);
            int q = lane & 3;
            f4 f;
            f.x = ldsw[(q*4 + 0)*68 + c];
            f.y = ldsw[(q*4 + 1)*68 + c];
            f.z = ldsw[(q*4 + 2)*68 + c];
            f.w = ldsw[(q*4 + 3)*68 + c];
            __builtin_nontemporal_store(f,
                (f4*)(outb + (size_t)c*(NYY*NXX) + rowoff + g*16 + q*4));
        }
    }
}

extern "C" void kernel_launch(void* const* d_in, const int* in_sizes, int n_in,
                              void* d_out, int out_size, void* d_ws, size_t ws_size,
                              hipStream_t stream) {
    const float* x          = (const float*)d_in[0];
    const float* rots       = (const float*)d_in[1];
    const float* trans      = (const float*)d_in[2];
    const float* intrins    = (const float*)d_in[3];
    const float* post_rots  = (const float*)d_in[4];
    const float* post_trans = (const float*)d_in[5];
    float* out = (float*)d_out;

    char* ws = (char*)d_ws;
    unsigned int* cntp  = (unsigned int*)(ws + W_CNT);
    unsigned int* table = (unsigned int*)(ws + W_TAB);

    hipMemsetAsync(cntp, 0, NVOX, stream);                 // 230 KB
    geom<<<NTRI/16, 256, 0, stream>>>(rots, trans, intrins, post_rots, post_trans,
                                      cntp, table);
    assemble<<<BB*NYY, 256, 0, stream>>>(x, cntp, table, out);   // 960 row-blocks
}

// Round 3
// 227.848 us; speedup vs baseline: 1.2891x; 1.2891x over previous
//
#include <hip/hip_runtime.h>

// ---- static problem config (mirrors reference init) ----
#define BB   4
#define NNC  4          // cameras
#define DDEP 41
#define FHH  16
#define FWW  44
#define CC   64
#define NXX  240
#define NYY  240
#define NVOX (BB*NYY*NXX)            // 230400 BEV cells (vz==0 plane)
#define NTRI (BB*NNC*DDEP*FWW)       // 28864 (b,n,d,u) column triples; < 2^15
#define SLOTS 8                      // max triples per cell (geometric bound ~4)

// ---- workspace layout (bytes) ----
#define W_CNT  0                         // uint cntp[NVOX/4]  (byte-packed counts)
#define W_TAB  (NVOX)                    // uint table[NVOX][SLOTS]  ((tri<<16)|mask)
// total = 230400 + 7372800 ~= 7.6 MB

typedef float f4 __attribute__((ext_vector_type(4)));

// Replicate LAPACK sgetrf+strti2 on an UPPER-TRIANGULAR 3x3 in fp32, op-for-op.
__device__ __forceinline__ void inv3x3_upper_f32(const float K[9], float o[9]) {
    float a00 = __fdiv_rn(1.0f, K[0]);
    float a11 = __fdiv_rn(1.0f, K[4]);
    float a22 = __fdiv_rn(1.0f, K[8]);
    float b01 = __fmul_rn(-a11, __fmul_rn(a00, K[1]));
    float x0 = __fadd_rn(__fmul_rn(a00, K[2]), __fmul_rn(b01, K[5]));
    float x1 = __fmul_rn(a11, K[5]);
    float b02 = __fmul_rn(-a22, x0);
    float b12 = __fmul_rn(-a22, x1);
    o[0]=a00; o[1]=b01; o[2]=b02;
    o[3]=0.0f; o[4]=a11; o[5]=b12;
    o[6]=0.0f; o[7]=0.0f; o[8]=a22;
}

// Pure-arithmetic geometry (UNCHANGED — bit-exact numerics verified).
__global__ void __launch_bounds__(256) geom(
        const float* __restrict__ rots,
        const float* __restrict__ trans,
        const float* __restrict__ intrins,
        const float* __restrict__ post_rots,
        const float* __restrict__ post_trans,
        unsigned int* __restrict__ cntp,
        unsigned int* __restrict__ table) {
    int wid  = threadIdx.x >> 6;
    int lane = threadIdx.x & 63;
    int sub  = lane >> 4;
    int h    = lane & 15;
    int tri  = (blockIdx.x*4 + wid)*4 + sub;     // NTRI = 16*1804 exactly

    int w    = tri % FWW;
    int rest = tri / FWW;
    int d    = rest % DDEP;
    int bn   = rest / DDEP;

    float K[9], PR[9], R[9];
    #pragma unroll
    for (int i = 0; i < 9; ++i) {
        K[i]  = intrins[bn*9 + i];
        PR[i] = post_rots[bn*9 + i];
        R[i]  = rots[bn*9 + i];
    }
    float Ki[9], PRi[9];
    inv3x3_upper_f32(K, Ki);
    inv3x3_upper_f32(PR, PRi);
    float C[9];
    #pragma unroll
    for (int i = 0; i < 3; ++i)
        #pragma unroll
        for (int j = 0; j < 3; ++j) {
            float s = __fmul_rn(R[i*3+0], Ki[0*3+j]);
            s = __fadd_rn(s, __fmul_rn(R[i*3+1], Ki[1*3+j]));
            s = __fadd_rn(s, __fmul_rn(R[i*3+2], Ki[2*3+j]));
            C[i*3+j] = s;
        }
    float ptx = post_trans[bn*3+0], pty = post_trans[bn*3+1], ptz = post_trans[bn*3+2];
    float trx = trans[bn*3+0], try_ = trans[bn*3+1], trz = trans[bn*3+2];

    float u  = (float)((double)w * (703.0/43.0));   // np.linspace: f64 then f32 cast
    float v  = (float)((double)h * 17.0);
    float dd = (float)(4 + d);

    float p0x = __fsub_rn(u,  ptx);
    float p0y = __fsub_rn(v,  pty);
    float p0z = __fsub_rn(dd, ptz);
    float p1x = __fadd_rn(__fadd_rn(__fmul_rn(PRi[0],p0x), __fmul_rn(PRi[1],p0y)), __fmul_rn(PRi[2],p0z));
    float p1y = __fadd_rn(__fadd_rn(__fmul_rn(PRi[3],p0x), __fmul_rn(PRi[4],p0y)), __fmul_rn(PRi[5],p0z));
    float p1z = __fadd_rn(__fadd_rn(__fmul_rn(PRi[6],p0x), __fmul_rn(PRi[7],p0y)), __fmul_rn(PRi[8],p0z));
    float p2x = __fmul_rn(p1x, p1z);
    float p2y = __fmul_rn(p1y, p1z);
    float p2z = p1z;
    float ex = __fadd_rn(__fadd_rn(__fmul_rn(C[0],p2x), __fmul_rn(C[1],p2y)), __fmul_rn(C[2],p2z));
    float ey = __fadd_rn(__fadd_rn(__fmul_rn(C[3],p2x), __fmul_rn(C[4],p2y)), __fmul_rn(C[5],p2z));
    float ez = __fadd_rn(__fadd_rn(__fmul_rn(C[6],p2x), __fmul_rn(C[7],p2y)), __fmul_rn(C[8],p2z));
    float gx = __fadd_rn(ex, trx);
    float gy = __fadd_rn(ey, try_);
    float gz = __fadd_rn(ez, trz);

    float qx = __fdiv_rn(__fsub_rn(gx, -48.0f), 0.4f);
    float qy = __fdiv_rn(__fsub_rn(gy, -48.0f), 0.4f);
    float qz = __fdiv_rn(__fsub_rn(gz, -10.0f), 20.0f);
    int vx = (int)qx;   // trunc toward zero == astype(int32)
    int vy = (int)qy;
    int vz = (int)qz;

    bool kept = (vx >= 0) & (vx < NXX) & (vy >= 0) & (vy < NYY) & (vz == 0);
    unsigned long long bal = __ballot(kept);
    unsigned int mask = (unsigned int)((bal >> (sub*16)) & 0xFFFFull);

    if (h == 0 && mask != 0) {
        int b  = bn / NNC;
        int vb = b*(NYY*NXX) + vy*NXX + vx;
        unsigned int sh  = 8u*(vb & 3);
        unsigned int old = atomicAdd(&cntp[vb >> 2], 1u << sh);
        unsigned int sl  = (old >> sh) & 0xFFu;
        if (sl < SLOTS) table[vb*SLOTS + sl] = ((unsigned int)tri << 16) | mask;
    }
}

// v4: 64 consecutive cells per 256-thread block (3600 blocks — occupancy
// restored vs v3's 960) with 256 B-contiguous writes per c-plane (write-row-
// locality restored vs v1's 64 B islands). Clean blocks (block-uniform ballot
// over all 64 counts) stream 16 KB of zeros with no LDS/no barrier. Dirty
// blocks keep v2's exact per-cell gather + shfl-reduce summation order
// (identical rounding), deposit per-cell channel vectors into a pad-65 LDS
// tile (~2-way bank aliasing only), one barrier, then transpose out as one
// 256 B run per plane per block.
__global__ void __launch_bounds__(256) assemble(
        const float* __restrict__ x,
        const unsigned int* __restrict__ cntp,
        const unsigned int* __restrict__ table,
        float* __restrict__ out) {
    __shared__ float lds[64*65];             // 16.6 KB: lds[cell*65 + channel]
    int tid  = threadIdx.x;
    int lane = tid & 63;
    int wid  = tid >> 6;
    int v0   = blockIdx.x * 64;              // first cell; 57600%64==0 -> no b-cross
    int b    = v0 / (NYY*NXX);
    int yx0  = v0 - b*(NYY*NXX);
    float* outb = out + (size_t)b*(CC*NYY*NXX) + yx0;

    // every wave loads the same 16 count words -> identical 64-bit dirty mask
    unsigned int cword = cntp[(v0 >> 2) + (lane >> 2)];
    unsigned int cbyte = (cword >> (8*(lane & 3))) & 0xFFu;
    unsigned long long dmask = __ballot(cbyte != 0u);    // block-uniform

    int sub = lane >> 4, xi = lane & 15;     // write-out mapping: 16 lanes = 256 B run

    if (dmask == 0ull) {
        f4 z = (f4)(0.0f);
        #pragma unroll
        for (int it = 0; it < 4; ++it) {
            int c = wid*16 + it*4 + sub;
            __builtin_nontemporal_store(z, (f4*)(outb + (size_t)c*(NYY*NXX) + xi*4));
        }
        return;
    }

    // ---- dirty block ----
    for (int i = tid; i < 64*65; i += 256) lds[i] = 0.0f;

    int hq = lane >> 4, c4 = lane & 15;
    unsigned long long m2 = dmask;
    int gi = 0;
    while (m2) {
        int cell = __ffsll((unsigned long long)m2) - 1;
        m2 &= m2 - 1;
        if ((gi++ & 3) != wid) continue;     // one cell per wave, round-robin

        int n = __shfl((int)cbyte, cell);
        if (n > SLOTS) n = SLOTS;
        unsigned int ent = (lane < n) ? table[(size_t)(v0 + cell)*SLOTS + lane] : 0u;

        f4 acc = (f4)(0.0f);
        for (int i = 0; i < n; ++i) {
            unsigned int e = (unsigned int)__shfl((int)ent, i);
            int tri  = (int)(e >> 16);
            unsigned int m = e & 0xFFFFu;
            int w    = tri % FWW;
            int rest = tri / FWW;
            int d    = rest % DDEP;
            int bn   = rest / DDEP;
            const float* xb = x + (size_t)((bn*DDEP + d)*FHH*FWW + w)*CC + c4*4;
            #pragma unroll
            for (int r = 0; r < 4; ++r) {
                int h = r*4 + hq;
                if ((m >> h) & 1u) {
                    f4 t = *(const f4*)(xb + (size_t)h*(FWW*CC));
                    acc += t;
                }
            }
        }
        // same reduce order as v2 -> identical rounding
        acc.x += __shfl_xor(acc.x, 16); acc.y += __shfl_xor(acc.y, 16);
        acc.z += __shfl_xor(acc.z, 16); acc.w += __shfl_xor(acc.w, 16);
        acc.x += __shfl_xor(acc.x, 32); acc.y += __shfl_xor(acc.y, 32);
        acc.z += __shfl_xor(acc.z, 32); acc.w += __shfl_xor(acc.w, 32);
        if (lane < 16) {                     // lane == c4: channels 4*c4..4*c4+3
            lds[cell*65 + c4*4 + 0] = acc.x;
            lds[cell*65 + c4*4 + 1] = acc.y;
            lds[cell*65 + c4*4 + 2] = acc.z;
            lds[cell*65 + c4*4 + 3] = acc.w;
        }
    }
    __syncthreads();

    // transpose out: per plane c one contiguous 256 B run (64 cells x 4 B)
    #pragma unroll
    for (int it = 0; it < 4; ++it) {
        int c = wid*16 + it*4 + sub;
        f4 f;
        f.x = lds[(xi*4 + 0)*65 + c];
        f.y = lds[(xi*4 + 1)*65 + c];
        f.z = lds[(xi*4 + 2)*65 + c];
        f.w = lds[(xi*4 + 3)*65 + c];
        __builtin_nontemporal_store(f, (f4*)(outb + (size_t)c*(NYY*NXX) + xi*4));
    }
}

extern "C" void kernel_launch(void* const* d_in, const int* in_sizes, int n_in,
                              void* d_out, int out_size, void* d_ws, size_t ws_size,
                              hipStream_t stream) {
    const float* x          = (const float*)d_in[0];
    const float* rots       = (const float*)d_in[1];
    const float* trans      = (const float*)d_in[2];
    const float* intrins    = (const float*)d_in[3];
    const float* post_rots  = (const float*)d_in[4];
    const float* post_trans = (const float*)d_in[5];
    float* out = (float*)d_out;

    char* ws = (char*)d_ws;
    unsigned int* cntp  = (unsigned int*)(ws + W_CNT);
    unsigned int* table = (unsigned int*)(ws + W_TAB);

    hipMemsetAsync(cntp, 0, NVOX, stream);                 // 230 KB
    geom<<<NTRI/16, 256, 0, stream>>>(rots, trans, intrins, post_rots, post_trans,
                                      cntp, table);
    assemble<<<NVOX/64, 256, 0, stream>>>(x, cntp, table, out);   // 3600 blocks
}